// Round 3
// baseline (112.275 us; speedup 1.0000x reference)
//
#include <hip/hip_runtime.h>
#include <hip/hip_bf16.h>
#include <math.h>

#define NB   256
#define KIN  1024
#define ND   512
#define NP   2048
#define NTOT 4096   // Wm rows + proxy rows stacked

typedef __bf16 bf16x8 __attribute__((ext_vector_type(8)));
typedef float  f32x4  __attribute__((ext_vector_type(4)));
typedef unsigned short ush8 __attribute__((ext_vector_type(8)));

// ws byte offsets (16B aligned)
#define OFF_WPB    0u          // 4096*512 bf16 = 4 MB
#define OFF_FEATB  4194304u    // 256*512 bf16  = 256 KB
#define OFF_PN2    4456448u    // 2048 f32
#define OFF_LOGITS 4464640u    // 256*2048 f32  = 2 MB
#define OFF_ROWLP  6561792u    // 256 f32
#define OFF_ROWNM  6562816u    // 256 f32

__device__ __forceinline__ float bf2f(unsigned short h) {
    union { unsigned u; float f; } v; v.u = ((unsigned)h) << 16; return v.f;
}

// pack 8 fp32 -> 8 bf16 (RNE) using packed cvt
__device__ __forceinline__ ush8 pack8(float4 f0, float4 f1) {
    union { ush8 v; __hip_bfloat162 h[4]; } o;
    o.h[0] = __float22bfloat162_rn(make_float2(f0.x, f0.y));
    o.h[1] = __float22bfloat162_rn(make_float2(f0.z, f0.w));
    o.h[2] = __float22bfloat162_rn(make_float2(f1.x, f1.y));
    o.h[3] = __float22bfloat162_rn(make_float2(f1.z, f1.w));
    return o.v;
}

// async 16B global->LDS DMA (dest = wave-uniform lds base + lane*16)
__device__ __forceinline__ void async16(const unsigned short* g, unsigned short* l) {
    __builtin_amdgcn_global_load_lds(
        (const __attribute__((address_space(1))) unsigned int*)g,
        (__attribute__((address_space(3))) unsigned int*)l, 16, 0, 0);
}

// ---------------------------------------------------------------------------
// K1 mega-kernel:
//  blocks [0,32):    feat GEMM 64x64 (inline fp32->bf16 staging, dbuf pipeline)
//  blocks [32,544):  cast Wm -> WPb[0:2048)
//  blocks [544,1056): cast prox -> WPb[2048:4096) + pn2
// ---------------------------------------------------------------------------
__global__ __launch_bounds__(256) void k_one(
    const float* __restrict__ x, const float* __restrict__ Wb,
    const float* __restrict__ bb, const float* __restrict__ Wm,
    const float* __restrict__ prox, unsigned short* __restrict__ featb,
    unsigned short* __restrict__ WPb, float* __restrict__ pn2)
{
    const int bid = blockIdx.x, t = threadIdx.x;
    const int lane = t & 63, w = t >> 6;
    if (bid < 32) {
        __shared__ unsigned short As[2][64 * 32];
        __shared__ unsigned short Bs[2][64 * 32];
        const int n0 = (bid & 7) * 64, m0 = (bid >> 3) * 64;
        const int srow = t >> 2, sc = (t & 3) * 8;
        const float* gA = x  + (size_t)(m0 + srow) * KIN + sc;
        const float* gB = Wb + (size_t)(n0 + srow) * KIN + sc;
        float4 a0 = *(const float4*)gA, a1 = *(const float4*)(gA + 4);
        float4 b0 = *(const float4*)gB, b1 = *(const float4*)(gB + 4);
        f32x4 acc[2][2] = {};
        const int wm = (w >> 1) * 32, wn = (w & 1) * 32;
        const int arow = wm + (lane & 15), brow = wn + (lane & 15);
        const int fcol = (lane >> 4) * 8;
        for (int ks = 0; ks < KIN / 32; ++ks) {
            *(ush8*)&As[ks & 1][srow * 32 + sc] = pack8(a0, a1);
            *(ush8*)&Bs[ks & 1][srow * 32 + sc] = pack8(b0, b1);
            __syncthreads();
            if (ks + 1 < KIN / 32) {   // prefetch next step, in flight under MFMA
                a0 = *(const float4*)(gA + (ks + 1) * 32);
                a1 = *(const float4*)(gA + (ks + 1) * 32 + 4);
                b0 = *(const float4*)(gB + (ks + 1) * 32);
                b1 = *(const float4*)(gB + (ks + 1) * 32 + 4);
            }
            const unsigned short* as = &As[ks & 1][0];
            const unsigned short* bs = &Bs[ks & 1][0];
            bf16x8 af0 = *(const bf16x8*)&as[(arow     ) * 32 + fcol];
            bf16x8 af1 = *(const bf16x8*)&as[(arow + 16) * 32 + fcol];
            bf16x8 bf0 = *(const bf16x8*)&bs[(brow     ) * 32 + fcol];
            bf16x8 bf1 = *(const bf16x8*)&bs[(brow + 16) * 32 + fcol];
            acc[0][0] = __builtin_amdgcn_mfma_f32_16x16x32_bf16(af0, bf0, acc[0][0], 0, 0, 0);
            acc[0][1] = __builtin_amdgcn_mfma_f32_16x16x32_bf16(af0, bf1, acc[0][1], 0, 0, 0);
            acc[1][0] = __builtin_amdgcn_mfma_f32_16x16x32_bf16(af1, bf0, acc[1][0], 0, 0, 0);
            acc[1][1] = __builtin_amdgcn_mfma_f32_16x16x32_bf16(af1, bf1, acc[1][1], 0, 0, 0);
        }
        const int q = lane >> 4, cn = lane & 15;
#pragma unroll
        for (int i = 0; i < 2; ++i)
#pragma unroll
            for (int j = 0; j < 2; ++j) {
                const int n = n0 + wn + 16 * j + cn;
                const float bias = bb[n];
#pragma unroll
                for (int r = 0; r < 4; ++r) {
                    const int m = m0 + wm + 16 * i + q * 4 + r;
                    featb[m * ND + n] = __hip_bfloat16_raw(__hip_bfloat16(acc[i][j][r] + bias)).x;
                }
            }
    } else if (bid < 544) {
        const int idx = (bid - 32) * 2048 + t * 8;
        float4 f0 = *(const float4*)(Wm + idx), f1 = *(const float4*)(Wm + idx + 4);
        *(ush8*)(WPb + idx) = pack8(f0, f1);
    } else {
        const int b = bid - 544;
        const int idx = b * 2048 + t * 8;
        float4 f0 = *(const float4*)(prox + idx), f1 = *(const float4*)(prox + idx + 4);
        *(ush8*)(WPb + (size_t)NP * ND + idx) = pack8(f0, f1);
        float s = f0.x*f0.x + f0.y*f0.y + f0.z*f0.z + f0.w*f0.w
                + f1.x*f1.x + f1.y*f1.y + f1.z*f1.z + f1.w*f1.w;
#pragma unroll
        for (int off = 32; off; off >>= 1) s += __shfl_down(s, off);
        if (lane == 0) pn2[b * 4 + w] = s;   // wave w owns row 4b+w (512 elems)
    }
}

// ---------------------------------------------------------------------------
// K2: head GEMM, 128x128 tile, DMA staging, dbuf pipeline.
//  n<2048: out = feat@Wm.T + bm ; n>=2048: logits = 2*feat@prox.T - pn2
// ---------------------------------------------------------------------------
__global__ __launch_bounds__(256) void k_head(
    const unsigned short* __restrict__ featb, const unsigned short* __restrict__ WPb,
    const float* __restrict__ bm, const float* __restrict__ pn2,
    float* __restrict__ out, float* __restrict__ logits)
{
    __shared__ unsigned short As[2][128 * 32];
    __shared__ unsigned short Bs[2][128 * 32];
    const int t = threadIdx.x, lane = t & 63, w = t >> 6;
    const int n0 = blockIdx.x * 128;   // 32 n-blocks over 4096
    const int m0 = blockIdx.y * 128;   // 2 m-blocks
    // per-lane global srcs for DMA rounds (round u covers rows u*64 + w*16 + lane/4)
    const int drow = w * 16 + (lane >> 2), dcol = (lane & 3) * 8;
    const unsigned short* gA0 = featb + (size_t)(m0 +      drow) * ND + dcol;
    const unsigned short* gA1 = featb + (size_t)(m0 + 64 + drow) * ND + dcol;
    const unsigned short* gB0 = WPb   + (size_t)(n0 +      drow) * ND + dcol;
    const unsigned short* gB1 = WPb   + (size_t)(n0 + 64 + drow) * ND + dcol;

#define ISSUE(buf, ks)                                              \
    do {                                                            \
        const int o_ = (ks) * 32;                                   \
        async16(gA0 + o_, &As[buf][(     w * 16) * 32]);            \
        async16(gA1 + o_, &As[buf][(64 + w * 16) * 32]);            \
        async16(gB0 + o_, &Bs[buf][(     w * 16) * 32]);            \
        async16(gB1 + o_, &Bs[buf][(64 + w * 16) * 32]);            \
    } while (0)

    f32x4 acc[4][4] = {};
    const int wm = (w >> 1) * 64, wn = (w & 1) * 64;
    const int fr = lane & 15, fcol = (lane >> 4) * 8;
    ISSUE(0, 0);
    for (int ks = 0; ks < ND / 32; ++ks) {
        __syncthreads();                       // drains DMA(ks); prev reads done
        if (ks + 1 < ND / 32) ISSUE((ks + 1) & 1, ks + 1);
        const unsigned short* as = &As[ks & 1][0];
        const unsigned short* bs = &Bs[ks & 1][0];
        bf16x8 af[4], bf[4];
#pragma unroll
        for (int i = 0; i < 4; ++i) af[i] = *(const bf16x8*)&as[(wm + 16 * i + fr) * 32 + fcol];
#pragma unroll
        for (int j = 0; j < 4; ++j) bf[j] = *(const bf16x8*)&bs[(wn + 16 * j + fr) * 32 + fcol];
#pragma unroll
        for (int i = 0; i < 4; ++i)
#pragma unroll
            for (int j = 0; j < 4; ++j)
                acc[i][j] = __builtin_amdgcn_mfma_f32_16x16x32_bf16(af[i], bf[j], acc[i][j], 0, 0, 0);
    }
#undef ISSUE
    const bool isProxy = (n0 >= NP);
    const int q = lane >> 4;
#pragma unroll
    for (int i = 0; i < 4; ++i)
#pragma unroll
        for (int j = 0; j < 4; ++j) {
            const int n = n0 + wn + 16 * j + fr;
            const float cadd = isProxy ? pn2[n - NP] : bm[n];
#pragma unroll
            for (int r = 0; r < 4; ++r) {
                const int m = m0 + wm + 16 * i + q * 4 + r;
                const float v = acc[i][j][r];
                if (isProxy) logits[m * NP + (n - NP)] = 2.0f * v - cadd;
                else         out[m * NP + n] = v + cadd;
            }
        }
}

__device__ __forceinline__ float block_reduce(float v, float* sred, int op)
{
    const int lane = threadIdx.x & 63, wave = threadIdx.x >> 6;
#pragma unroll
    for (int off = 32; off; off >>= 1) {
        float o = __shfl_down(v, off);
        v = op ? fmaxf(v, o) : (v + o);
    }
    if (lane == 0) sred[wave] = v;
    __syncthreads();
    if (threadIdx.x == 0) {
        float r = sred[0];
#pragma unroll
        for (int wv = 1; wv < 4; ++wv) r = op ? fmaxf(r, sred[wv]) : (r + sred[wv]);
        sred[0] = r;
    }
    __syncthreads();
    float r = sred[0];
    __syncthreads();
    return r;
}

// K3: per-row logsumexp + target gather + feat row-norm
__global__ __launch_bounds__(256) void k_loss(
    const unsigned short* __restrict__ featb, const float* __restrict__ logits,
    const int* __restrict__ y, float* __restrict__ rowlp, float* __restrict__ rownm)
{
    __shared__ float sred[4];
    const int b = blockIdx.x, t = threadIdx.x;

    float s = 0.f;
#pragma unroll
    for (int c = 0; c < 2; ++c) {
        float v = bf2f(featb[b * ND + t * 2 + c]); s += v * v;
    }
    float fn2 = block_reduce(s, sred, 0);

    const float* lr = logits + (size_t)b * NP;
    float lv[8], mx = -INFINITY;
#pragma unroll
    for (int j = 0; j < 8; ++j) { lv[j] = lr[t + 256 * j]; mx = fmaxf(mx, lv[j]); }
    float MX = block_reduce(mx, sred, 1);
    float es = 0.f;
#pragma unroll
    for (int j = 0; j < 8; ++j) es += __expf(lv[j] - MX);
    float SUM = block_reduce(es, sred, 0);

    if (t == 0) {
        float ly = lr[y[b]];
        rowlp[b] = ly - MX - __logf(SUM);
        rownm[b] = sqrtf(fn2);
    }
}

__global__ __launch_bounds__(256) void k_final(
    const float* __restrict__ rowlp, const float* __restrict__ rownm,
    float* __restrict__ tail)
{
    __shared__ float sred[4];
    const int t = threadIdx.x;
    float s1 = block_reduce(rowlp[t], sred, 0);
    float s2 = block_reduce(rownm[t], sred, 0);
    if (t == 0) {
        tail[0] = -s1 / (float)NB;
        tail[1] =  s2 / (float)NB;
    }
}

extern "C" void kernel_launch(void* const* d_in, const int* in_sizes, int n_in,
                              void* d_out, int out_size, void* d_ws, size_t ws_size,
                              hipStream_t stream)
{
    const float* x       = (const float*)d_in[0];
    const int*   y       = (const int*)  d_in[1];
    const float* Wb      = (const float*)d_in[2];
    const float* bb      = (const float*)d_in[3];
    const float* Wm      = (const float*)d_in[4];
    const float* bm      = (const float*)d_in[5];
    const float* proxies = (const float*)d_in[6];

    char* ws = (char*)d_ws;
    unsigned short* WPb    = (unsigned short*)(ws + OFF_WPB);
    unsigned short* featb  = (unsigned short*)(ws + OFF_FEATB);
    float*          pn2    = (float*)(ws + OFF_PN2);
    float*          logits = (float*)(ws + OFF_LOGITS);
    float*          rowlp  = (float*)(ws + OFF_ROWLP);
    float*          rownm  = (float*)(ws + OFF_ROWNM);

    float* out  = (float*)d_out;
    float* tail = out + (size_t)NB * NP;

    k_one <<<dim3(1056), dim3(256), 0, stream>>>(x, Wb, bb, Wm, proxies, featb, WPb, pn2);
    k_head<<<dim3(NTOT / 128, NB / 128), dim3(256), 0, stream>>>(featb, WPb, bm, pn2, out, logits);
    k_loss<<<dim3(NB), dim3(256), 0, stream>>>(featb, logits, y, rowlp, rownm);
    k_final<<<dim3(1), dim3(256), 0, stream>>>(rowlp, rownm, tail);
}